// Round 5
// baseline (344.730 us; speedup 1.0000x reference)
//
#include <hip/hip_runtime.h>
#include <cstdint>

#define R_TOT 16384
#define T_NT  2048
#define DD    128
#define HH    512
#define MC_   20
#define BR    32             // rows per block in k3
#define STEPS 64             // 2048 / 32 cols
#define NBLK  (R_TOT / BR)   // 512

// Output layout (floats)
#define MASK_OFF 0
#define LOGP_OFF 16384
#define WORD_OFF 32768
#define CHAR_OFF 49152
#define EMB_OFF  376832          // 49152 + 16384*20
#define LOSS_OFF 2473984         // 376832 + 16384*128

// ws layout (float slots)
#define X_OFF     0              // x f32 [16384][128]
#define HDN_OFF   2097152        // hdn f32 [16384][512]
#define HDNB_OFF  10485760       // hdn bf16 ushort[16384*512]
#define WT_OFF    14680064       // wtgt f32 [2048][128]
#define WTT_OFF   14942208       // wtgtT3 bf16 ushort[64][8][16][32]
#define W2T_OFF   15073280       // W2T f32 [2048][512]
#define W2TB_OFF  16121856       // W2T bf16 ushort[2048*512]
#define ENT_OFF   16646144       // 512
#define CNT_OFF   16647168       // 512

typedef __attribute__((ext_vector_type(8))) short short8v;
typedef __attribute__((ext_vector_type(4))) float f32x4;
typedef unsigned short ushort_t;

__device__ __forceinline__ ushort_t f2bf(float f) {
    union { float f; unsigned int u; } v; v.f = f;
    unsigned int r = v.u + 0x7FFFu + ((v.u >> 16) & 1u);
    return (ushort_t)(r >> 16);
}

// ---------------- K1: gather embeddings ----------------
__global__ __launch_bounds__(256) void k1_gather(
    const int* __restrict__ inp_word, const int* __restrict__ tgt_ids,
    const float* __restrict__ W, float* __restrict__ x, float* __restrict__ wtgt)
{
    int row = blockIdx.x * 2 + (threadIdx.x >> 7);
    int d = threadIdx.x & 127;
    if (row < R_TOT) {
        int wsrc = inp_word[row];
        x[(size_t)row * DD + d] = W[(size_t)wsrc * DD + d];
    } else {
        int rr = row - R_TOT;
        if (rr < T_NT) {
            int wsrc = tgt_ids[rr];
            wtgt[(size_t)rr * DD + d] = W[(size_t)wsrc * DD + d];
        }
    }
}

// ---------------- K1b: wtgt [2048][128] -> wtgtT3 bf16 [kt][dt][dl][ki] ----------------
// wtgtT3[((kt*8 + dt)*16 + dl)*32 + ki] = bf16(wtgt[kt*32+ki][dt*16+dl])
__global__ __launch_bounds__(256) void k1b_wtgtT3(
    const float* __restrict__ wtgt, ushort_t* __restrict__ wtgtT3)
{
    __shared__ float tile[32][33];
    int tb = blockIdx.x * 32, db = blockIdx.y * 32;
    int lx = threadIdx.x & 31, ly = threadIdx.x >> 5;
    #pragma unroll
    for (int i = 0; i < 32; i += 8)
        tile[ly + i][lx] = wtgt[(size_t)(tb + ly + i) * DD + db + lx];
    __syncthreads();
    int kt = tb >> 5;
    #pragma unroll
    for (int i = 0; i < 32; i += 8) {
        int d = db + ly + i;
        wtgtT3[(size_t)(((kt * 8 + (d >> 4)) * 16 + (d & 15)) * 32) + lx] =
            f2bf(tile[lx][ly + i]);
    }
}

// ---------------- K0: W2 [512][2048] -> W2T f32+bf16 [2048][512] ----------------
__global__ __launch_bounds__(256) void k0_w2t(
    const float* __restrict__ W2, float* __restrict__ W2Tf, ushort_t* __restrict__ W2Tb)
{
    __shared__ float tile[32][33];
    int cb = blockIdx.x * 32, kb = blockIdx.y * 32;
    int lx = threadIdx.x & 31, ly = threadIdx.x >> 5;
    #pragma unroll
    for (int i = 0; i < 32; i += 8)
        tile[ly + i][lx] = W2[(size_t)(kb + ly + i) * T_NT + cb + lx];
    __syncthreads();
    #pragma unroll
    for (int i = 0; i < 32; i += 8) {
        int c = cb + ly + i, k = kb + lx;
        float v = tile[lx][ly + i];
        W2Tf[(size_t)c * HH + k] = v;
        W2Tb[(size_t)c * HH + k] = f2bf(v);
    }
}

// ---------------- K2: hdn = relu(x @ W1 + b1), fp32 + bf16 outputs ----------------
__global__ __launch_bounds__(256) void k2_hdn(
    const float* __restrict__ x, const float* __restrict__ W1,
    const float* __restrict__ b1, float* __restrict__ hdn, ushort_t* __restrict__ hdnB)
{
    __shared__ float As[16][64];
    __shared__ float Bs[16][64];
    const int t = threadIdx.x;
    const int bm = blockIdx.x * 64;
    const int bn = blockIdx.y * 64;
    const int tx = t & 15, ty = t >> 4;
    float acc[4][4] = {};
    for (int k0 = 0; k0 < DD; k0 += 16) {
        {
            int m = t >> 2, kq = t & 3;
            float4 v = *(const float4*)(x + (size_t)(bm + m) * DD + k0 + kq * 4);
            As[kq * 4 + 0][m] = v.x; As[kq * 4 + 1][m] = v.y;
            As[kq * 4 + 2][m] = v.z; As[kq * 4 + 3][m] = v.w;
        }
        {
            int k = t >> 4, nq = t & 15;
            *(float4*)(&Bs[k][nq * 4]) =
                *(const float4*)(W1 + (size_t)(k0 + k) * HH + bn + nq * 4);
        }
        __syncthreads();
        #pragma unroll
        for (int k = 0; k < 16; ++k) {
            float a[4], b[4];
            #pragma unroll
            for (int i = 0; i < 4; i++) a[i] = As[k][ty * 4 + i];
            #pragma unroll
            for (int j = 0; j < 4; j++) b[j] = Bs[k][tx * 4 + j];
            #pragma unroll
            for (int i = 0; i < 4; i++)
                #pragma unroll
                for (int j = 0; j < 4; j++)
                    acc[i][j] = fmaf(a[i], b[j], acc[i][j]);
        }
        __syncthreads();
    }
    #pragma unroll
    for (int i = 0; i < 4; i++) {
        int m = bm + ty * 4 + i;
        int n = bn + tx * 4;
        float4 v;
        v.x = fmaxf(acc[i][0] + b1[n + 0], 0.f);
        v.y = fmaxf(acc[i][1] + b1[n + 1], 0.f);
        v.z = fmaxf(acc[i][2] + b1[n + 2], 0.f);
        v.w = fmaxf(acc[i][3] + b1[n + 3], 0.f);
        *(float4*)(hdn + (size_t)m * HH + n) = v;
        ushort4 hb;
        hb.x = f2bf(v.x); hb.y = f2bf(v.y); hb.z = f2bf(v.z); hb.w = f2bf(v.w);
        *(ushort4*)(hdnB + (size_t)m * HH + n) = hb;
    }
}

// ---------------- K3: barrier-free streaming fused kernel ----------------
// 512 blocks x 32 rows, 4 independent waves = 2 Mgrp x 2 col-split.
// Wave (mg, cw): rows mg*16..+16, steps js = cw, cw+2, ..., 62/63 (32 cols each).
// No barriers in main loop: B from L2, A from swizzled shared aS, private P-LDS.
__global__ __launch_bounds__(256, 2) void k3_fused(
    const ushort_t* __restrict__ hdnB, const float* __restrict__ hdn,
    const ushort_t* __restrict__ W2Tb, const float* __restrict__ W2Tf,
    const float* __restrict__ b2, const float* __restrict__ gumbel,
    const int* __restrict__ inp_word, const int* __restrict__ keyword_table,
    const int* __restrict__ tgt_ids, const int* __restrict__ lut,
    const float* __restrict__ x, const ushort_t* __restrict__ wtgtT3,
    float* __restrict__ out, float* __restrict__ entP, float* __restrict__ cntP)
{
    __shared__ ushort_t aS[BR * 512];        // 32 KB swizzled A; reused as merge scratch
    __shared__ float pS[4][16 * 36];         // per-wave P tile
    __shared__ float statP[4][16][8];
    __shared__ int   candS[BR * 2];
    __shared__ float invs2S[BR], entS[BR];
    __shared__ int   mskS[BR];

    const int t = threadIdx.x;
    const int wid = t >> 6, lane = t & 63;
    const int mg = wid >> 1, cw = wid & 1;
    const int lrow = lane & 15, kgrp = lane >> 4;
    const int row0 = blockIdx.x * BR;

    // ---- stage A (hdnB rows) into swizzled aS: granule g -> g ^ (row&7) ----
    {
        #pragma unroll
        for (int i = 0; i < 8; ++i) {
            int fid = i * 256 + t;            // 2048 granules (32 rows x 64)
            int row = fid >> 6, g = fid & 63;
            uint4 v = *(const uint4*)(hdnB + (size_t)(row0 + row) * HH + g * 8);
            *(uint4*)(aS + row * 512 + ((g ^ (row & 7)) << 3)) = v;
        }
    }
    __syncthreads();

    // ---- A read bases (conflict-free swizzle decomposition) ----
    const int r7 = lrow & 7;
    const int bpar = (lrow >> 2) & 1;
    const ushort_t* baseC = aS + (mg * 16 + lrow) * 512 + ((kgrp ^ (r7 & 3)) << 3);
    const ushort_t* baseE = baseC + bpar * 32;   // even ks: +bpar*64B
    const ushort_t* baseO = baseC - bpar * 32;   // odd ks:  -bpar*64B

    // ---- running pointers ----
    const ushort_t* bp0 = W2Tb + (size_t)(cw * 32 + lrow) * HH + kgrp * 8;
    const ushort_t* bp1 = bp0 + 16 * HH;
    const float* gp[4];
    #pragma unroll
    for (int q = 0; q < 4; ++q)
        gp[q] = gumbel + (size_t)(row0 + mg * 16 + kgrp * 4 + q) * T_NT + cw * 32 + lrow;
    const float* b2p = b2 + cw * 32 + lrow;
    const ushort_t* vt3p = wtgtT3 + (size_t)cw * 4096 + lrow * 32 + kgrp * 8;

    float* pw = &pS[wid][0];

    // ---- stats ----
    float m_[4], sE_[4], sEl_[4], s2_[4], a1_[4], a2_[4];
    int i1_[4], i2_[4];
    #pragma unroll
    for (int q = 0; q < 4; ++q) {
        m_[q] = -1e30f; sE_[q] = 0.f; sEl_[q] = 0.f; s2_[q] = 0.f;
        a1_[q] = -1e30f; a2_[q] = -1e30f; i1_[q] = 0; i2_[q] = 0;
    }
    f32x4 accpv[8];
    #pragma unroll
    for (int df = 0; df < 8; ++df) accpv[df] = (f32x4){0.f, 0.f, 0.f, 0.f};

    // ---- gumbel preload for first step ----
    float gcur[8];
    #pragma unroll
    for (int q = 0; q < 4; ++q) { gcur[2 * q] = gp[q][0]; gcur[2 * q + 1] = gp[q][16]; }

    for (int js = cw; js < STEPS; js += 2) {
        // prefetch next step's gumbel (guarded)
        const int nadv = (js + 2 < STEPS) ? 64 : 0;
        float gnx[8];
        #pragma unroll
        for (int q = 0; q < 4; ++q) {
            gnx[2 * q] = gp[q][nadv];
            gnx[2 * q + 1] = gp[q][nadv + 16];
        }
        float b2lo = b2p[0], b2hi = b2p[16];

        // -- S: 16 K-slices, 8 independent chains, A from LDS (reused x2), B from L2 --
        f32x4 c0[4], c1[4];
        #pragma unroll
        for (int j = 0; j < 4; ++j) { c0[j] = (f32x4){0.f,0.f,0.f,0.f}; c1[j] = c0[j]; }
        #pragma unroll
        for (int ks = 0; ks < 16; ++ks) {
            const ushort_t* ab = (ks & 1) ? baseO : baseE;
            short8v a = *(const short8v*)(ab + ks * 32);
            short8v bv0 = *(const short8v*)(bp0 + ks * 32);
            short8v bv1 = *(const short8v*)(bp1 + ks * 32);
            c0[ks & 3] = __builtin_amdgcn_mfma_f32_16x16x32_bf16(a, bv0, c0[ks & 3], 0, 0, 0);
            c1[ks & 3] = __builtin_amdgcn_mfma_f32_16x16x32_bf16(a, bv1, c1[ks & 3], 0, 0, 0);
        }
        f32x4 acc0 = (c0[0] + c0[1]) + (c0[2] + c0[3]);
        f32x4 acc1 = (c1[0] + c1[1]) + (c1[2] + c1[3]);

        // -- stats + top2 + P (both 16-col tiles) --
        const int col0 = js * 32 + lrow;
        #pragma unroll
        for (int q = 0; q < 4; ++q) {
            float l0 = acc0[q] + b2lo;
            m_[q] = fmaxf(m_[q], l0);
            float e0 = __expf(l0);
            sE_[q] += e0; sEl_[q] = fmaf(e0, l0, sEl_[q]);
            float aa0 = l0 + gcur[2 * q];
            float p0 = __expf(2.0f * aa0);
            s2_[q] += p0;
            if (aa0 > a1_[q]) { a2_[q] = a1_[q]; i2_[q] = i1_[q]; a1_[q] = aa0; i1_[q] = col0; }
            else if (aa0 > a2_[q]) { a2_[q] = aa0; i2_[q] = col0; }
            pw[(kgrp * 4 + q) * 36 + lrow] = p0;

            float l1 = acc1[q] + b2hi;
            m_[q] = fmaxf(m_[q], l1);
            float e1 = __expf(l1);
            sE_[q] += e1; sEl_[q] = fmaf(e1, l1, sEl_[q]);
            float aa1 = l1 + gcur[2 * q + 1];
            float p1 = __expf(2.0f * aa1);
            s2_[q] += p1;
            if (aa1 > a1_[q]) { a2_[q] = a1_[q]; i2_[q] = i1_[q]; a1_[q] = aa1; i1_[q] = col0 + 16; }
            else if (aa1 > a2_[q]) { a2_[q] = aa1; i2_[q] = col0 + 16; }
            pw[(kgrp * 4 + q) * 36 + 16 + lrow] = p1;
        }

        // -- PV: same-wave LDS transpose read (compiler-ordered), 8 d-tiles --
        {
            const float* pr = pw + lrow * 36 + kgrp * 8;
            float4 pa = *(const float4*)(pr);
            float4 pb = *(const float4*)(pr + 4);
            short8v pav;
            pav[0] = (short)f2bf(pa.x); pav[1] = (short)f2bf(pa.y);
            pav[2] = (short)f2bf(pa.z); pav[3] = (short)f2bf(pa.w);
            pav[4] = (short)f2bf(pb.x); pav[5] = (short)f2bf(pb.y);
            pav[6] = (short)f2bf(pb.z); pav[7] = (short)f2bf(pb.w);
            #pragma unroll
            for (int df = 0; df < 8; ++df) {
                short8v bv = *(const short8v*)(vt3p + df * 512);
                accpv[df] = __builtin_amdgcn_mfma_f32_16x16x32_bf16(pav, bv, accpv[df], 0, 0, 0);
            }
        }

        // -- advance --
        bp0 += 64 * HH; bp1 += 64 * HH;
        #pragma unroll
        for (int q = 0; q < 4; ++q) gp[q] += 64;
        b2p += 64; vt3p += 8192;
        #pragma unroll
        for (int j = 0; j < 8; ++j) gcur[j] = gnx[j];
    }

    // ---- in-wave reduction over the 16 lrow lanes ----
    #pragma unroll
    for (int q = 0; q < 4; ++q) {
        #pragma unroll
        for (int mk = 1; mk < 16; mk <<= 1) {
            m_[q] = fmaxf(m_[q], __shfl_xor(m_[q], mk));
            sE_[q] += __shfl_xor(sE_[q], mk);
            sEl_[q] += __shfl_xor(sEl_[q], mk);
            s2_[q] += __shfl_xor(s2_[q], mk);
            float ob1 = __shfl_xor(a1_[q], mk); int oj1 = __shfl_xor(i1_[q], mk);
            float ob2 = __shfl_xor(a2_[q], mk); int oj2 = __shfl_xor(i2_[q], mk);
            if (ob1 > a1_[q] || (ob1 == a1_[q] && oj1 < i1_[q])) {
                if (a1_[q] > ob2 || (a1_[q] == ob2 && i1_[q] < oj2)) { a2_[q] = a1_[q]; i2_[q] = i1_[q]; }
                else { a2_[q] = ob2; i2_[q] = oj2; }
                a1_[q] = ob1; i1_[q] = oj1;
            } else {
                if (ob1 > a2_[q]) { a2_[q] = ob1; i2_[q] = oj1; }
            }
        }
    }

    // ---- phase 1: publish partials (stats; cw==1 also PV partials into scratch) ----
    if (lrow == 0) {
        #pragma unroll
        for (int q = 0; q < 4; ++q) {
            float* st = &statP[wid][kgrp * 4 + q][0];
            st[0] = m_[q]; st[1] = sE_[q]; st[2] = sEl_[q]; st[3] = s2_[q];
            st[4] = a1_[q]; st[5] = __int_as_float(i1_[q]);
            st[6] = a2_[q]; st[7] = __int_as_float(i2_[q]);
        }
    }
    float* scr = (float*)aS;   // 32 KB scratch: [mg][16][132]
    if (cw == 1) {
        #pragma unroll
        for (int df = 0; df < 8; ++df)
            #pragma unroll
            for (int q = 0; q < 4; ++q)
                scr[mg * 2112 + (kgrp * 4 + q) * 132 + df * 16 + lrow] = accpv[df][q];
    }
    __syncthreads();

    // ---- phase 2: cw==0 merges ----
    if (cw == 0) {
        #pragma unroll
        for (int q = 0; q < 4; ++q) {
            int r = kgrp * 4 + q;
            const float* st = &statP[mg * 2 + 1][r][0];
            float bm = st[0], bsE = st[1], bsEl = st[2], bs2 = st[3];
            float ob1 = st[4]; int oj1 = __float_as_int(st[5]);
            float ob2 = st[6]; int oj2 = __float_as_int(st[7]);
            float m = fmaxf(m_[q], bm);
            float sE = sE_[q] + bsE, sEl = sEl_[q] + bsEl, s2 = s2_[q] + bs2;
            float a1 = a1_[q], a2 = a2_[q]; int i1 = i1_[q], i2 = i2_[q];
            if (ob1 > a1 || (ob1 == a1 && oj1 < i1)) {
                if (a1 > ob2 || (a1 == ob2 && i1 < oj2)) { a2 = a1; i2 = i1; }
                else { a2 = ob2; i2 = oj2; }
                a1 = ob1; i1 = oj1;
            } else {
                if (ob1 > a2) { a2 = ob1; i2 = oj1; }
            }
            if (lrow == 0) {
                int rl = mg * 16 + r;
                int grow = row0 + rl;
                int w_in = inp_word[grow];
                int msk = keyword_table[w_in] != 0;
                out[MASK_OFF + grow] = msk ? 1.0f : 0.0f;
                out[LOGP_OFF + grow] = msk ? m : 0.0f;
                invs2S[rl] = 1.0f / s2;
                mskS[rl] = msk;
                entS[rl] = msk ? (__logf(sE) - sEl / sE) : 0.0f;
                candS[rl * 2 + 0] = i1;
                candS[rl * 2 + 1] = i2;
            }
        }
        #pragma unroll
        for (int df = 0; df < 8; ++df)
            #pragma unroll
            for (int q = 0; q < 4; ++q)
                accpv[df][q] += scr[mg * 2112 + (kgrp * 4 + q) * 132 + df * 16 + lrow];
    }
    __syncthreads();

    // ---- x_emb store (cw==0 waves) ----
    if (cw == 0) {
        #pragma unroll
        for (int df = 0; df < 8; ++df) {
            #pragma unroll
            for (int q = 0; q < 4; ++q) {
                int rl = mg * 16 + kgrp * 4 + q;
                int grow = row0 + rl;
                int d = df * 16 + lrow;
                float val = accpv[df][q] * invs2S[rl];
                if (!mskS[rl]) val = x[(size_t)grow * DD + d];
                out[EMB_OFF + (size_t)grow * DD + d] = val;
            }
        }
    }

    // ---- repair + word/char outputs: wave wid handles rows wid, wid+4, ... ----
    for (int rr = wid; rr < BR; rr += 4) {
        int grow = row0 + rr;
        int i1 = candS[rr * 2 + 0], i2 = candS[rr * 2 + 1];
        const float* hrow = hdn + (size_t)grow * HH;
        float4 h0 = *(const float4*)(hrow + lane * 8);
        float4 h1 = *(const float4*)(hrow + lane * 8 + 4);
        float v1, v2;
        {
            const float* wrow = W2Tf + (size_t)i1 * HH;
            float4 w0 = *(const float4*)(wrow + lane * 8);
            float4 w1 = *(const float4*)(wrow + lane * 8 + 4);
            float sdot = h0.x*w0.x + h0.y*w0.y + h0.z*w0.z + h0.w*w0.w
                       + h1.x*w1.x + h1.y*w1.y + h1.z*w1.z + h1.w*w1.w;
            #pragma unroll
            for (int mk = 1; mk < 64; mk <<= 1) sdot += __shfl_xor(sdot, mk);
            v1 = sdot + b2[i1] + gumbel[(size_t)grow * T_NT + i1];
        }
        {
            const float* wrow = W2Tf + (size_t)i2 * HH;
            float4 w0 = *(const float4*)(wrow + lane * 8);
            float4 w1 = *(const float4*)(wrow + lane * 8 + 4);
            float sdot = h0.x*w0.x + h0.y*w0.y + h0.z*w0.z + h0.w*w0.w
                       + h1.x*w1.x + h1.y*w1.y + h1.z*w1.z + h1.w*w1.w;
            #pragma unroll
            for (int mk = 1; mk < 64; mk <<= 1) sdot += __shfl_xor(sdot, mk);
            v2 = sdot + b2[i2] + gumbel[(size_t)grow * T_NT + i2];
        }
        int ibest = (v2 > v1 || (v2 == v1 && i2 < i1)) ? i2 : i1;
        int w_in = inp_word[grow];
        int msk = mskS[rr];
        int word = msk ? tgt_ids[ibest] : w_in;
        if (lane == 0) out[WORD_OFF + grow] = (float)word;
        if (lane < MC_)
            out[CHAR_OFF + (size_t)grow * MC_ + lane] = (float)lut[(size_t)word * MC_ + lane];
    }

    if (t == 0) {
        float es = 0.f; int cs = 0;
        #pragma unroll
        for (int r = 0; r < BR; r++) { es += entS[r]; cs += mskS[r]; }
        entP[blockIdx.x] = es;
        cntP[blockIdx.x] = (float)cs;
    }
}

// ---------------- K4: final loss reduction ----------------
__global__ __launch_bounds__(256) void k4_loss(
    const float* __restrict__ entP, const float* __restrict__ cntP, float* __restrict__ out)
{
    __shared__ float sE[256], sC[256];
    int t = threadIdx.x;
    float e = 0.f, c = 0.f;
    for (int i = t; i < NBLK; i += 256) { e += entP[i]; c += cntP[i]; }
    sE[t] = e; sC[t] = c;
    __syncthreads();
    for (int s = 128; s > 0; s >>= 1) {
        if (t < s) { sE[t] += sE[t + s]; sC[t] += sC[t + s]; }
        __syncthreads();
    }
    if (t == 0) {
        float ns = fmaxf(sC[0], 1.0f);
        out[LOSS_OFF] = 0.03f * sE[0] / ns;
    }
}

// ---------------- launch ----------------
extern "C" void kernel_launch(void* const* d_in, const int* in_sizes, int n_in,
                              void* d_out, int out_size, void* d_ws, size_t ws_size,
                              hipStream_t stream) {
    const int* inp_word = (const int*)d_in[0];
    const int* keyword_table = (const int*)d_in[3];
    const int* tgt_ids = (const int*)d_in[4];
    const int* lut = (const int*)d_in[5];
    const float* gumbel = (const float*)d_in[6];
    const float* W = (const float*)d_in[7];
    const float* W1 = (const float*)d_in[8];
    const float* b1 = (const float*)d_in[9];
    const float* W2 = (const float*)d_in[10];
    const float* b2 = (const float*)d_in[11];
    float* out = (float*)d_out;

    float* wsf = (float*)d_ws;
    float* x = wsf + X_OFF;
    float* hdn = wsf + HDN_OFF;
    ushort_t* hdnB = (ushort_t*)(wsf + HDNB_OFF);
    float* wtgt = wsf + WT_OFF;
    ushort_t* wtgtT3 = (ushort_t*)(wsf + WTT_OFF);
    float* W2Tf = wsf + W2T_OFF;
    ushort_t* W2Tb = (ushort_t*)(wsf + W2TB_OFF);
    float* entP = wsf + ENT_OFF;
    float* cntP = wsf + CNT_OFF;

    k1_gather<<<(R_TOT + T_NT) / 2, 256, 0, stream>>>(inp_word, tgt_ids, W, x, wtgt);
    k1b_wtgtT3<<<dim3(T_NT / 32, DD / 32), 256, 0, stream>>>(wtgt, wtgtT3);
    k0_w2t<<<dim3(T_NT / 32, HH / 32), 256, 0, stream>>>(W2, W2Tf, W2Tb);
    k2_hdn<<<dim3(R_TOT / 64, HH / 64), 256, 0, stream>>>(x, W1, b1, hdn, hdnB);
    k3_fused<<<NBLK, 256, 0, stream>>>(hdnB, hdn, W2Tb, W2Tf, b2, gumbel,
                                       inp_word, keyword_table, tgt_ids, lut,
                                       x, wtgtT3, out, entP, cntP);
    k4_loss<<<1, 256, 0, stream>>>(entP, cntP, out);
}

// Round 6
// 215.797 us; speedup vs baseline: 1.5975x; 1.5975x over previous
//
#include <hip/hip_runtime.h>
#include <cstdint>

#define R_TOT 16384
#define T_NT  2048
#define DD    128
#define HH    512
#define MC_   20
#define BR    32             // rows per block in k3
#define STEPS 64             // 2048 / 32 cols
#define NBLK  (R_TOT / BR)   // 512

// Output layout (floats)
#define MASK_OFF 0
#define LOGP_OFF 16384
#define WORD_OFF 32768
#define CHAR_OFF 49152
#define EMB_OFF  376832          // 49152 + 16384*20
#define LOSS_OFF 2473984         // 376832 + 16384*128

// ws layout (float slots)
#define X_OFF     0              // x f32 [16384][128]
#define HDN_OFF   2097152        // hdn f32 [16384][512]
#define HDNB_OFF  10485760       // hdn bf16 ushort[16384*512]
#define WT_OFF    14680064       // wtgt f32 [2048][128]
#define WTT4_OFF  14942208       // wtgtT4 ushort[64][2][8][64][8]  (524288)
#define W2T_OFF   15204352       // W2Tf f32 [2048][512]
#define W2P_OFF   16252928       // W2p ushort[64][16][32][4][8]    (1048576)
#define ENT_OFF   16777216       // 512
#define CNT_OFF   16777728       // 512

typedef __attribute__((ext_vector_type(8))) short short8v;
typedef __attribute__((ext_vector_type(4))) float f32x4;
typedef unsigned short ushort_t;

__device__ __forceinline__ ushort_t f2bf(float f) {
    union { float f; unsigned int u; } v; v.f = f;
    unsigned int r = v.u + 0x7FFFu + ((v.u >> 16) & 1u);
    return (ushort_t)(r >> 16);
}

__device__ __forceinline__ void stage16(const ushort_t* gsrc, ushort_t* ldst) {
    __builtin_amdgcn_global_load_lds(
        (const __attribute__((address_space(1))) unsigned int*)gsrc,
        (__attribute__((address_space(3))) unsigned int*)ldst, 16, 0, 0);
}

// ---------------- K1: gather embeddings ----------------
__global__ __launch_bounds__(256) void k1_gather(
    const int* __restrict__ inp_word, const int* __restrict__ tgt_ids,
    const float* __restrict__ W, float* __restrict__ x, float* __restrict__ wtgt)
{
    int row = blockIdx.x * 2 + (threadIdx.x >> 7);
    int d = threadIdx.x & 127;
    if (row < R_TOT) {
        int wsrc = inp_word[row];
        x[(size_t)row * DD + d] = W[(size_t)wsrc * DD + d];
    } else {
        int rr = row - R_TOT;
        if (rr < T_NT) {
            int wsrc = tgt_ids[rr];
            wtgt[(size_t)rr * DD + d] = W[(size_t)wsrc * DD + d];
        }
    }
}

// ---------------- K1b: wtgt -> wtgtT4 PV B-fragment pack ----------------
// wtgtT4[((js*2+cs)*8+df)*512 + lane*8 + j] =
//   j<4 ? bf16(wtgt[js*32+cs*16+(lane>>4)*4+j][df*16+(lane&15)]) : 0
__global__ __launch_bounds__(256) void k1b_wtgtT4(
    const float* __restrict__ wtgt, ushort_t* __restrict__ wtgtT4)
{
    const int js = blockIdx.x, t = threadIdx.x;
    #pragma unroll
    for (int i = 0; i < 4; ++i) {
        int s = i * 256 + t;
        int cs = s >> 9, rem = s & 511;
        int df = rem >> 6, lane = rem & 63;
        int lrow = lane & 15, kg = lane >> 4;
        ushort_t* dst = wtgtT4 + (size_t)(((js * 2 + cs) * 8 + df) * 512 + lane * 8);
        #pragma unroll
        for (int j = 0; j < 8; ++j) {
            dst[j] = (j < 4)
                ? f2bf(wtgt[(size_t)(js * 32 + cs * 16 + kg * 4 + j) * DD + df * 16 + lrow])
                : (ushort_t)0;
        }
    }
}

// ---------------- K0: W2 [512][2048] -> W2Tf f32 + W2p fragment pack ----------------
// W2p chunk (js,ks): 1024 ushorts; offset (c*4+kgrp)*8+i = bf16(W2[ks*32+kgrp*8+i][js*32+c])
__global__ __launch_bounds__(256) void k0_w2t(
    const float* __restrict__ W2, float* __restrict__ W2Tf, ushort_t* __restrict__ W2p)
{
    __shared__ float tile[32][33];
    const int js = blockIdx.x, ks = blockIdx.y;
    const int cb = js * 32, kb = ks * 32;
    const int lx = threadIdx.x & 31, ly = threadIdx.x >> 5;
    #pragma unroll
    for (int i = 0; i < 32; i += 8)
        tile[ly + i][lx] = W2[(size_t)(kb + ly + i) * T_NT + cb + lx];
    __syncthreads();
    #pragma unroll
    for (int i = 0; i < 32; i += 8) {
        int c = cb + ly + i, k = kb + lx;
        W2Tf[(size_t)c * HH + k] = tile[lx][ly + i];
    }
    if (threadIdx.x < 128) {
        int c = threadIdx.x >> 2, kgrp = threadIdx.x & 3;
        ushort_t* dst = W2p + (size_t)((js * 16 + ks) * 1024 + (c * 4 + kgrp) * 8);
        #pragma unroll
        for (int i = 0; i < 8; ++i)
            dst[i] = f2bf(tile[kgrp * 8 + i][c]);
    }
}

// ---------------- K2: hdn = relu(x @ W1 + b1), fp32 + bf16 outputs ----------------
__global__ __launch_bounds__(256) void k2_hdn(
    const float* __restrict__ x, const float* __restrict__ W1,
    const float* __restrict__ b1, float* __restrict__ hdn, ushort_t* __restrict__ hdnB)
{
    __shared__ float As[16][64];
    __shared__ float Bs[16][64];
    const int t = threadIdx.x;
    const int bm = blockIdx.x * 64;
    const int bn = blockIdx.y * 64;
    const int tx = t & 15, ty = t >> 4;
    float acc[4][4] = {};
    for (int k0 = 0; k0 < DD; k0 += 16) {
        {
            int m = t >> 2, kq = t & 3;
            float4 v = *(const float4*)(x + (size_t)(bm + m) * DD + k0 + kq * 4);
            As[kq * 4 + 0][m] = v.x; As[kq * 4 + 1][m] = v.y;
            As[kq * 4 + 2][m] = v.z; As[kq * 4 + 3][m] = v.w;
        }
        {
            int k = t >> 4, nq = t & 15;
            *(float4*)(&Bs[k][nq * 4]) =
                *(const float4*)(W1 + (size_t)(k0 + k) * HH + bn + nq * 4);
        }
        __syncthreads();
        #pragma unroll
        for (int k = 0; k < 16; ++k) {
            float a[4], b[4];
            #pragma unroll
            for (int i = 0; i < 4; i++) a[i] = As[k][ty * 4 + i];
            #pragma unroll
            for (int j = 0; j < 4; j++) b[j] = Bs[k][tx * 4 + j];
            #pragma unroll
            for (int i = 0; i < 4; i++)
                #pragma unroll
                for (int j = 0; j < 4; j++)
                    acc[i][j] = fmaf(a[i], b[j], acc[i][j]);
        }
        __syncthreads();
    }
    #pragma unroll
    for (int i = 0; i < 4; i++) {
        int m = bm + ty * 4 + i;
        int n = bn + tx * 4;
        float4 v;
        v.x = fmaxf(acc[i][0] + b1[n + 0], 0.f);
        v.y = fmaxf(acc[i][1] + b1[n + 1], 0.f);
        v.z = fmaxf(acc[i][2] + b1[n + 2], 0.f);
        v.w = fmaxf(acc[i][3] + b1[n + 3], 0.f);
        *(float4*)(hdn + (size_t)m * HH + n) = v;
        ushort4 hb;
        hb.x = f2bf(v.x); hb.y = f2bf(v.y); hb.z = f2bf(v.z); hb.w = f2bf(v.w);
        *(ushort4*)(hdnB + (size_t)m * HH + n) = hb;
    }
}

// ---------------- K3: staged streaming fused kernel, 1 barrier/step ----------------
// 512 blocks x 32 rows, 4 waves = 2 Mgrp x 2 Cgrp (16-col halves). P wave-private.
__global__ __launch_bounds__(256) void k3_fused(
    const ushort_t* __restrict__ hdnB, const float* __restrict__ hdn,
    const ushort_t* __restrict__ W2p, const float* __restrict__ W2Tf,
    const float* __restrict__ b2, const float* __restrict__ gumbel,
    const int* __restrict__ inp_word, const int* __restrict__ keyword_table,
    const int* __restrict__ tgt_ids, const int* __restrict__ lut,
    const float* __restrict__ x, const ushort_t* __restrict__ wtgtT4,
    float* __restrict__ out, float* __restrict__ entP, float* __restrict__ cntP)
{
    __shared__ ushort_t wS[2 * 16384];      // 64 KB double-buffered W2p tiles; scratch later
    __shared__ float pS[4][16 * 20];        // wave-private P transpose (pad 20)
    __shared__ float statC1[2 * 16 * 8];
    __shared__ int   candS[BR * 2];
    __shared__ float invs2S[BR], entS[BR];
    __shared__ int   mskS[BR];

    const int t = threadIdx.x;
    const int wid = t >> 6, lane = t & 63;
    const int Mgrp = wid >> 1, Cgrp = wid & 1;
    const int lrow = lane & 15, kgrp = lane >> 4;
    const int row0 = blockIdx.x * BR;
    const int rowA = row0 + Mgrp * 16 + lrow;

    // ---- A fragments: full K in registers ----
    short8v av[16];
    #pragma unroll
    for (int ks = 0; ks < 16; ++ks)
        av[ks] = *(const short8v*)(hdnB + (size_t)rowA * HH + ks * 32 + kgrp * 8);

    // ---- B read base (loop-invariant + ks*1024 ushort imm) ----
    const ushort_t* wb = wS + ((Cgrp * 16 + lrow) * 4 + kgrp) * 8;

    // ---- running pointers ----
    const float* gp0 = gumbel + (size_t)(row0 + Mgrp * 16 + kgrp * 4 + 0) * T_NT + Cgrp * 16 + lrow;
    const float* gp1 = gp0 + T_NT;
    const float* gp2 = gp1 + T_NT;
    const float* gp3 = gp2 + T_NT;
    const float* b2p = b2 + Cgrp * 16 + lrow;
    const ushort_t* vtp = wtgtT4 + (size_t)Cgrp * 4096 + lane * 8;

    float* pw = &pS[wid][0];

    // ---- stats ----
    float m_[4], sE_[4], sEl_[4], s2_[4], a1_[4], a2_[4];
    int i1_[4], i2_[4];
    #pragma unroll
    for (int q = 0; q < 4; ++q) {
        m_[q] = -1e30f; sE_[q] = 0.f; sEl_[q] = 0.f; s2_[q] = 0.f;
        a1_[q] = -1e30f; a2_[q] = -1e30f; i1_[q] = 0; i2_[q] = 0;
    }
    f32x4 accpv[8];
    #pragma unroll
    for (int df = 0; df < 8; ++df) accpv[df] = (f32x4){0.f, 0.f, 0.f, 0.f};

    // ---- prologue: stage tile 0 into buf 0 ----
    {
        const ushort_t* src = W2p + t * 8;
        ushort_t* dst = wS + t * 8;
        #pragma unroll
        for (int i = 0; i < 8; ++i) stage16(src + i * 2048, dst + i * 2048);
    }
    __syncthreads();

    int colv = Cgrp * 16 + lrow;

    for (int s = 0; s < STEPS; ++s) {
        const int buf = s & 1;

        // 1) prefetch next W2p tile into buf^1 (linear copy)
        if (s + 1 < STEPS) {
            const ushort_t* src = W2p + (size_t)(s + 1) * 16384 + t * 8;
            ushort_t* dst = wS + (buf ^ 1) * 16384 + t * 8;
            #pragma unroll
            for (int i = 0; i < 8; ++i) stage16(src + i * 2048, dst + i * 2048);
        }

        // 2) early register loads (consumed late; latency hidden)
        float g0 = *gp0, g1 = *gp1, g2 = *gp2, g3 = *gp3;
        gp0 += 32; gp1 += 32; gp2 += 32; gp3 += 32;
        float b2v = *b2p; b2p += 32;
        short8v bvf[8];
        #pragma unroll
        for (int df = 0; df < 8; ++df)
            bvf[df] = *(const short8v*)(vtp + df * 512);
        vtp += 8192;

        // 3) S tile: 16 MFMA, 4 independent chains, conflict-free imm ds_reads
        const ushort_t* wbb = wb + buf * 16384;
        f32x4 ac0 = (f32x4){0.f,0.f,0.f,0.f}, ac1 = ac0, ac2 = ac0, ac3 = ac0;
        #pragma unroll
        for (int ks = 0; ks < 16; ks += 4) {
            ac0 = __builtin_amdgcn_mfma_f32_16x16x32_bf16(av[ks+0], *(const short8v*)(wbb + (ks+0)*1024), ac0, 0, 0, 0);
            ac1 = __builtin_amdgcn_mfma_f32_16x16x32_bf16(av[ks+1], *(const short8v*)(wbb + (ks+1)*1024), ac1, 0, 0, 0);
            ac2 = __builtin_amdgcn_mfma_f32_16x16x32_bf16(av[ks+2], *(const short8v*)(wbb + (ks+2)*1024), ac2, 0, 0, 0);
            ac3 = __builtin_amdgcn_mfma_f32_16x16x32_bf16(av[ks+3], *(const short8v*)(wbb + (ks+3)*1024), ac3, 0, 0, 0);
        }
        f32x4 acc = (ac0 + ac1) + (ac2 + ac3);

        // 4) stats + top2 + P write (wave-private, [row][col] pad-20)
        float g4[4] = {g0, g1, g2, g3};
        #pragma unroll
        for (int q = 0; q < 4; ++q) {
            float l = acc[q] + b2v;
            m_[q] = fmaxf(m_[q], l);
            float e1 = __expf(l);
            sE_[q] += e1; sEl_[q] = fmaf(e1, l, sEl_[q]);
            float a = l + g4[q];
            float p = __expf(2.0f * a);
            s2_[q] += p;
            if (a > a1_[q]) { a2_[q] = a1_[q]; i2_[q] = i1_[q]; a1_[q] = a; i1_[q] = colv; }
            else if (a > a2_[q]) { a2_[q] = a; i2_[q] = colv; }
            pw[(kgrp * 4 + q) * 20 + lrow] = p;
        }

        // 5) PV: transpose-read own P (same-wave, compiler-ordered), K=16 zero-padded
        {
            float4 p4 = *(const float4*)(pw + lrow * 20 + kgrp * 4);
            short8v pav;
            pav[0] = (short)f2bf(p4.x); pav[1] = (short)f2bf(p4.y);
            pav[2] = (short)f2bf(p4.z); pav[3] = (short)f2bf(p4.w);
            pav[4] = 0; pav[5] = 0; pav[6] = 0; pav[7] = 0;
            #pragma unroll
            for (int df = 0; df < 8; ++df)
                accpv[df] = __builtin_amdgcn_mfma_f32_16x16x32_bf16(pav, bvf[df], accpv[df], 0, 0, 0);
        }

        // 6) single end-of-step barrier (staging issued ~full step ago -> drain free)
        __syncthreads();
        colv += 32;
    }

    // ---- in-wave reduction over the 16 lrow lanes ----
    #pragma unroll
    for (int q = 0; q < 4; ++q) {
        #pragma unroll
        for (int mk = 1; mk < 16; mk <<= 1) {
            m_[q] = fmaxf(m_[q], __shfl_xor(m_[q], mk));
            sE_[q] += __shfl_xor(sE_[q], mk);
            sEl_[q] += __shfl_xor(sEl_[q], mk);
            s2_[q] += __shfl_xor(s2_[q], mk);
            float ob1 = __shfl_xor(a1_[q], mk); int oj1 = __shfl_xor(i1_[q], mk);
            float ob2 = __shfl_xor(a2_[q], mk); int oj2 = __shfl_xor(i2_[q], mk);
            if (ob1 > a1_[q] || (ob1 == a1_[q] && oj1 < i1_[q])) {
                if (a1_[q] > ob2 || (a1_[q] == ob2 && i1_[q] < oj2)) { a2_[q] = a1_[q]; i2_[q] = i1_[q]; }
                else { a2_[q] = ob2; i2_[q] = oj2; }
                a1_[q] = ob1; i1_[q] = oj1;
            } else {
                if (ob1 > a2_[q]) { a2_[q] = ob1; i2_[q] = oj1; }
            }
        }
    }

    // ---- phase 1: Cgrp1 publishes stats + PV partials ----
    if (Cgrp == 1 && lrow == 0) {
        #pragma unroll
        for (int q = 0; q < 4; ++q) {
            float* st = &statC1[(Mgrp * 16 + kgrp * 4 + q) * 8];
            st[0] = m_[q]; st[1] = sE_[q]; st[2] = sEl_[q]; st[3] = s2_[q];
            st[4] = a1_[q]; st[5] = __int_as_float(i1_[q]);
            st[6] = a2_[q]; st[7] = __int_as_float(i2_[q]);
        }
    }
    float* scr = (float*)wS;   // 16 KB scratch: [Mgrp][16 rows][128 d]
    if (Cgrp == 1) {
        #pragma unroll
        for (int df = 0; df < 8; ++df)
            #pragma unroll
            for (int q = 0; q < 4; ++q)
                scr[Mgrp * 2048 + (kgrp * 4 + q) * 128 + df * 16 + lrow] = accpv[df][q];
    }
    __syncthreads();

    // ---- phase 2: Cgrp0 merges + writes scalar outputs ----
    if (Cgrp == 0) {
        #pragma unroll
        for (int q = 0; q < 4; ++q) {
            int r = kgrp * 4 + q;
            const float* st = &statC1[(Mgrp * 16 + r) * 8];
            float bm = st[0], bsE = st[1], bsEl = st[2], bs2 = st[3];
            float ob1 = st[4]; int oj1 = __float_as_int(st[5]);
            float ob2 = st[6]; int oj2 = __float_as_int(st[7]);
            float m = fmaxf(m_[q], bm);
            float sE = sE_[q] + bsE, sEl = sEl_[q] + bsEl, s2 = s2_[q] + bs2;
            float a1 = a1_[q], a2 = a2_[q]; int i1 = i1_[q], i2 = i2_[q];
            if (ob1 > a1 || (ob1 == a1 && oj1 < i1)) {
                if (a1 > ob2 || (a1 == ob2 && i1 < oj2)) { a2 = a1; i2 = i1; }
                else { a2 = ob2; i2 = oj2; }
                a1 = ob1; i1 = oj1;
            } else {
                if (ob1 > a2) { a2 = ob1; i2 = oj1; }
            }
            if (lrow == 0) {
                int rl = Mgrp * 16 + r;
                int grow = row0 + rl;
                int w_in = inp_word[grow];
                int msk = keyword_table[w_in] != 0;
                out[MASK_OFF + grow] = msk ? 1.0f : 0.0f;
                out[LOGP_OFF + grow] = msk ? m : 0.0f;
                invs2S[rl] = 1.0f / s2;
                mskS[rl] = msk;
                entS[rl] = msk ? (__logf(sE) - sEl / sE) : 0.0f;
                candS[rl * 2 + 0] = i1;
                candS[rl * 2 + 1] = i2;
            }
        }
        #pragma unroll
        for (int df = 0; df < 8; ++df)
            #pragma unroll
            for (int q = 0; q < 4; ++q)
                accpv[df][q] += scr[Mgrp * 2048 + (kgrp * 4 + q) * 128 + df * 16 + lrow];
    }
    __syncthreads();

    // ---- x_emb store (Cgrp0 waves, full d) ----
    if (Cgrp == 0) {
        #pragma unroll
        for (int df = 0; df < 8; ++df) {
            #pragma unroll
            for (int q = 0; q < 4; ++q) {
                int rl = Mgrp * 16 + kgrp * 4 + q;
                int grow = row0 + rl;
                int d = df * 16 + lrow;
                float val = accpv[df][q] * invs2S[rl];
                if (!mskS[rl]) val = x[(size_t)grow * DD + d];
                out[EMB_OFF + (size_t)grow * DD + d] = val;
            }
        }
    }

    // ---- repair + word/char outputs: wave wid handles rows wid, wid+4, ... ----
    for (int rr = wid; rr < BR; rr += 4) {
        int grow = row0 + rr;
        int i1 = candS[rr * 2 + 0], i2 = candS[rr * 2 + 1];
        const float* hrow = hdn + (size_t)grow * HH;
        float4 h0 = *(const float4*)(hrow + lane * 8);
        float4 h1 = *(const float4*)(hrow + lane * 8 + 4);
        float v1, v2;
        {
            const float* wrow = W2Tf + (size_t)i1 * HH;
            float4 w0 = *(const float4*)(wrow + lane * 8);
            float4 w1 = *(const float4*)(wrow + lane * 8 + 4);
            float sdot = h0.x*w0.x + h0.y*w0.y + h0.z*w0.z + h0.w*w0.w
                       + h1.x*w1.x + h1.y*w1.y + h1.z*w1.z + h1.w*w1.w;
            #pragma unroll
            for (int mk = 1; mk < 64; mk <<= 1) sdot += __shfl_xor(sdot, mk);
            v1 = sdot + b2[i1] + gumbel[(size_t)grow * T_NT + i1];
        }
        {
            const float* wrow = W2Tf + (size_t)i2 * HH;
            float4 w0 = *(const float4*)(wrow + lane * 8);
            float4 w1 = *(const float4*)(wrow + lane * 8 + 4);
            float sdot = h0.x*w0.x + h0.y*w0.y + h0.z*w0.z + h0.w*w0.w
                       + h1.x*w1.x + h1.y*w1.y + h1.z*w1.z + h1.w*w1.w;
            #pragma unroll
            for (int mk = 1; mk < 64; mk <<= 1) sdot += __shfl_xor(sdot, mk);
            v2 = sdot + b2[i2] + gumbel[(size_t)grow * T_NT + i2];
        }
        int ibest = (v2 > v1 || (v2 == v1 && i2 < i1)) ? i2 : i1;
        int w_in = inp_word[grow];
        int msk = mskS[rr];
        int word = msk ? tgt_ids[ibest] : w_in;
        if (lane == 0) out[WORD_OFF + grow] = (float)word;
        if (lane < MC_)
            out[CHAR_OFF + (size_t)grow * MC_ + lane] = (float)lut[(size_t)word * MC_ + lane];
    }

    if (t == 0) {
        float es = 0.f; int cs = 0;
        #pragma unroll
        for (int r = 0; r < BR; r++) { es += entS[r]; cs += mskS[r]; }
        entP[blockIdx.x] = es;
        cntP[blockIdx.x] = (float)cs;
    }
}

// ---------------- K4: final loss reduction ----------------
__global__ __launch_bounds__(256) void k4_loss(
    const float* __restrict__ entP, const float* __restrict__ cntP, float* __restrict__ out)
{
    __shared__ float sE[256], sC[256];
    int t = threadIdx.x;
    float e = 0.f, c = 0.f;
    for (int i = t; i < NBLK; i += 256) { e += entP[i]; c += cntP[i]; }
    sE[t] = e; sC[t] = c;
    __syncthreads();
    for (int s = 128; s > 0; s >>= 1) {
        if (t < s) { sE[t] += sE[t + s]; sC[t] += sC[t + s]; }
        __syncthreads();
    }
    if (t == 0) {
        float ns = fmaxf(sC[0], 1.0f);
        out[LOSS_OFF] = 0.03f * sE[0] / ns;
    }
}

// ---------------- launch ----------------
extern "C" void kernel_launch(void* const* d_in, const int* in_sizes, int n_in,
                              void* d_out, int out_size, void* d_ws, size_t ws_size,
                              hipStream_t stream) {
    const int* inp_word = (const int*)d_in[0];
    const int* keyword_table = (const int*)d_in[3];
    const int* tgt_ids = (const int*)d_in[4];
    const int* lut = (const int*)d_in[5];
    const float* gumbel = (const float*)d_in[6];
    const float* W = (const float*)d_in[7];
    const float* W1 = (const float*)d_in[8];
    const float* b1 = (const float*)d_in[9];
    const float* W2 = (const float*)d_in[10];
    const float* b2 = (const float*)d_in[11];
    float* out = (float*)d_out;

    float* wsf = (float*)d_ws;
    float* x = wsf + X_OFF;
    float* hdn = wsf + HDN_OFF;
    ushort_t* hdnB = (ushort_t*)(wsf + HDNB_OFF);
    float* wtgt = wsf + WT_OFF;
    ushort_t* wtgtT4 = (ushort_t*)(wsf + WTT4_OFF);
    float* W2Tf = wsf + W2T_OFF;
    ushort_t* W2p = (ushort_t*)(wsf + W2P_OFF);
    float* entP = wsf + ENT_OFF;
    float* cntP = wsf + CNT_OFF;

    k1_gather<<<(R_TOT + T_NT) / 2, 256, 0, stream>>>(inp_word, tgt_ids, W, x, wtgt);
    k1b_wtgtT4<<<64, 256, 0, stream>>>(wtgt, wtgtT4);
    k0_w2t<<<dim3(T_NT / 32, HH / 32), 256, 0, stream>>>(W2, W2Tf, W2p);
    k2_hdn<<<dim3(R_TOT / 64, HH / 64), 256, 0, stream>>>(x, W1, b1, hdn, hdnB);
    k3_fused<<<NBLK, 256, 0, stream>>>(hdnB, hdn, W2p, W2Tf, b2, gumbel,
                                       inp_word, keyword_table, tgt_ids, lut,
                                       x, wtgtT4, out, entP, cntP);
    k4_loss<<<1, 256, 0, stream>>>(entP, cntP, out);
}